// Round 1
// baseline (218.371 us; speedup 1.0000x reference)
//
#include <hip/hip_runtime.h>
#include <math.h>

// Problem constants (B, SK, SQ, H, D, N) = (4, 4096, 4096, 16, 64, 32)
#define BB 4
#define SK 4096
#define SQ 4096
#define HH 16
#define DD 64
#define NN 32
#define NCHUNK 8
#define KPC (SK / NCHUNK)   // 512 keys per chunk
#define KBATCH 64           // keys staged per LDS batch

// freqs[n] = (n / (N-1)) * N * pi
__device__ __forceinline__ float freq_of(int n) {
    return (float)n * (32.0f * (float)M_PI / 31.0f);
}

// ---------------------------------------------------------------------------
// Kernel 1: partial C/S sums.  C[n,d] = sum_k cos(f_n * key_k) * v[k,d],
// S likewise with sin.  Grid: 512 blocks = 64 (b,h) pairs x 8 K-chunks.
// Thread layout: d4 = tid&15 (4 consecutive d via float4), ng = tid>>4 (2 n's).
// sincos staged in LDS per 64-key batch (8 sincos/thread/batch).
// Partial layout: P[chunk][bh][cs][n][d]  (cs: 0=C, 1=S)
// ---------------------------------------------------------------------------
__global__ __launch_bounds__(256) void k1_partial(
    const float* __restrict__ key_in, const float* __restrict__ value,
    float* __restrict__ P)
{
    const int chunk = blockIdx.x & (NCHUNK - 1);
    const int bh    = blockIdx.x >> 3;
    const int b = bh >> 4, h = bh & 15;
    const int tid = threadIdx.x;
    const int d4 = tid & 15, ng = tid >> 4;
    const int d0 = d4 * 4, n0 = ng * 2;

    __shared__ float2 csK[KBATCH][NN];   // 16 KB: (cos, sin) per (key, n)

    float accC0[4] = {0,0,0,0}, accS0[4] = {0,0,0,0};
    float accC1[4] = {0,0,0,0}, accS1[4] = {0,0,0,0};

    for (int bb = 0; bb < KPC / KBATCH; ++bb) {
        const int kbase = chunk * KPC + bb * KBATCH;
        // --- stage sincos for this key batch (KBATCH*NN = 2048 pairs) ---
        #pragma unroll
        for (int i = 0; i < (KBATCH * NN) / 256; ++i) {  // 8 per thread
            int idx = tid + i * 256;
            int kl = idx >> 5, n = idx & 31;
            float kv = key_in[(size_t)(b * SK + kbase + kl) * HH + h];
            float s, c;
            __sincosf(freq_of(n) * kv, &s, &c);
            csK[kl][n] = make_float2(c, s);
        }
        __syncthreads();

        const float* vbase = value + (size_t)(b * SK + kbase) * (HH * DD) + h * DD + d0;
        #pragma unroll 4
        for (int kl = 0; kl < KBATCH; ++kl) {
            float4 v = *(const float4*)(vbase + (size_t)kl * (HH * DD));
            float2 cs0 = csK[kl][n0];
            float2 cs1 = csK[kl][n0 + 1];
            accC0[0] += cs0.x * v.x; accC0[1] += cs0.x * v.y;
            accC0[2] += cs0.x * v.z; accC0[3] += cs0.x * v.w;
            accS0[0] += cs0.y * v.x; accS0[1] += cs0.y * v.y;
            accS0[2] += cs0.y * v.z; accS0[3] += cs0.y * v.w;
            accC1[0] += cs1.x * v.x; accC1[1] += cs1.x * v.y;
            accC1[2] += cs1.x * v.z; accC1[3] += cs1.x * v.w;
            accS1[0] += cs1.y * v.x; accS1[1] += cs1.y * v.y;
            accS1[2] += cs1.y * v.z; accS1[3] += cs1.y * v.w;
        }
        __syncthreads();
    }

    // write partials
    float* Pb = P + ((size_t)chunk * 64 + bh) * (2 * NN * DD);
    *(float4*)(Pb + (size_t)n0 * DD + d0)             = make_float4(accC0[0], accC0[1], accC0[2], accC0[3]);
    *(float4*)(Pb + (size_t)(n0 + 1) * DD + d0)       = make_float4(accC1[0], accC1[1], accC1[2], accC1[3]);
    *(float4*)(Pb + 2048 + (size_t)n0 * DD + d0)      = make_float4(accS0[0], accS0[1], accS0[2], accS0[3]);
    *(float4*)(Pb + 2048 + (size_t)(n0 + 1) * DD + d0) = make_float4(accS1[0], accS1[1], accS1[2], accS1[3]);
}

// ---------------------------------------------------------------------------
// Kernel 1b: reduce the 8 chunk partials.  CS[bh][cs][n][d] (262144 floats).
// ---------------------------------------------------------------------------
__global__ __launch_bounds__(256) void k1_reduce(
    const float* __restrict__ P, float* __restrict__ CS)
{
    int gid = blockIdx.x * 256 + threadIdx.x;  // 0 .. 262143
    float acc = 0.f;
    #pragma unroll
    for (int c = 0; c < NCHUNK; ++c)
        acc += P[(size_t)c * (64 * 2 * NN * DD) + gid];
    CS[gid] = acc;
}

// ---------------------------------------------------------------------------
// Kernel 2: out[q,d] = sum_n A[q,n]*C[n,d] + B[q,n]*S[n,d]
// A = ra*cos(f_n q) + ia*sin(f_n q);  B = ra*sin(f_n q) - ia*cos(f_n q)
// Grid: 4096 blocks = 64 (b,h) x 64 q-chunks of 64 queries.
// Thread: d4 = tid&15 (4 d), qg = tid>>4 (4 q) -> 4x4 register tile.
// ---------------------------------------------------------------------------
__global__ __launch_bounds__(256) void k2_out(
    const float* __restrict__ query, const float* __restrict__ ramps,
    const float* __restrict__ iamps, const float* __restrict__ CS,
    float* __restrict__ out)
{
    const int bh = blockIdx.x >> 6;
    const int qc = blockIdx.x & 63;
    const int b = bh >> 4, h = bh & 15;
    const int qbase = qc * 64;
    const int tid = threadIdx.x;

    __shared__ float  csC[NN][DD];        // 8 KB  (C plane)
    __shared__ float  csS[NN][DD];        // 8 KB  (S plane)
    __shared__ float2 abL[64][NN + 1];    // ~17 KB, padded: ql stride 66 dwords

    // load C/S planes (each 2048 floats), coalesced
    const float* CSb = CS + (size_t)bh * (2 * NN * DD);
    #pragma unroll
    for (int i = 0; i < 8; ++i) {
        int idx = tid + i * 256;
        ((float*)csC)[idx] = CSb[idx];
        ((float*)csS)[idx] = CSb[2048 + idx];
    }
    // stage A/B for 64 queries x 32 n  (8 sincos per thread)
    #pragma unroll
    for (int i = 0; i < 8; ++i) {
        int idx = tid + i * 256;
        int ql = idx >> 5, n = idx & 31;
        float qv = query[(size_t)(b * SQ + qbase + ql) * HH + h];
        float ra = ramps[h * NN + n], ia = iamps[h * NN + n];
        float s, c;
        __sincosf(freq_of(n) * qv, &s, &c);
        abL[ql][n] = make_float2(ra * c + ia * s, ra * s - ia * c);
    }
    __syncthreads();

    const int d4 = tid & 15, qg = tid >> 4;
    const int d0 = d4 * 4;
    float acc[4][4];
    #pragma unroll
    for (int qi = 0; qi < 4; ++qi)
        #pragma unroll
        for (int dj = 0; dj < 4; ++dj) acc[qi][dj] = 0.f;

    #pragma unroll 2
    for (int n = 0; n < NN; ++n) {
        float4 c4 = *(const float4*)&csC[n][d0];
        float4 s4 = *(const float4*)&csS[n][d0];
        #pragma unroll
        for (int qi = 0; qi < 4; ++qi) {
            float2 ab = abL[qg * 4 + qi][n];
            acc[qi][0] += ab.x * c4.x + ab.y * s4.x;
            acc[qi][1] += ab.x * c4.y + ab.y * s4.y;
            acc[qi][2] += ab.x * c4.z + ab.y * s4.z;
            acc[qi][3] += ab.x * c4.w + ab.y * s4.w;
        }
    }

    float* ob = out + (size_t)(b * SQ + qbase) * (HH * DD) + h * DD + d0;
    #pragma unroll
    for (int qi = 0; qi < 4; ++qi) {
        int q = qg * 4 + qi;
        *(float4*)(ob + (size_t)q * (HH * DD)) =
            make_float4(acc[qi][0], acc[qi][1], acc[qi][2], acc[qi][3]);
    }
}

extern "C" void kernel_launch(void* const* d_in, const int* in_sizes, int n_in,
                              void* d_out, int out_size, void* d_ws, size_t ws_size,
                              hipStream_t stream) {
    const float* key_in = (const float*)d_in[0];
    const float* value  = (const float*)d_in[1];
    const float* query  = (const float*)d_in[2];
    const float* ramps  = (const float*)d_in[3];
    const float* iamps  = (const float*)d_in[4];
    float* out = (float*)d_out;

    // workspace: P = 8 chunks x 64 bh x 4096 floats (8 MB), CS = 1 MB after it
    float* P  = (float*)d_ws;
    float* CS = P + (size_t)NCHUNK * 64 * 2 * NN * DD;

    hipLaunchKernelGGL(k1_partial, dim3(64 * NCHUNK), dim3(256), 0, stream,
                       key_in, value, P);
    hipLaunchKernelGGL(k1_reduce, dim3((64 * 2 * NN * DD) / 256), dim3(256), 0, stream,
                       P, CS);
    hipLaunchKernelGGL(k2_out, dim3(64 * 64), dim3(256), 0, stream,
                       query, ramps, iamps, CS, out);
}

// Round 2
// 213.462 us; speedup vs baseline: 1.0230x; 1.0230x over previous
//
#include <hip/hip_runtime.h>
#include <math.h>

// Problem constants (B, SK, SQ, H, D, N) = (4, 4096, 4096, 16, 64, 32)
#define SK 4096
#define SQ 4096
#define HH 16
#define DD 64
#define NN 32
#define KBATCH 64           // keys staged per LDS batch

// freqs[n] = (n / (N-1)) * N * pi
__device__ __forceinline__ float freq_of(int n) {
    return (float)n * (32.0f * (float)M_PI / 31.0f);
}

// ---------------------------------------------------------------------------
// Kernel 1: partial C/S sums.  C[n,d] = sum_k cos(f_n * key_k) * v[k,d],
// S likewise with sin.  Grid: 64 (b,h) pairs x NC K-chunks.
// Thread layout: d4 = tid&15 (4 consecutive d via float4), ng = tid>>4 (2 n's).
// sincos staged in LDS per 64-key batch (8 sincos/thread/batch).
// Partial layout: P[chunk][bh][cs][n][d]  (cs: 0=C, 1=S)
// NC=32 -> 2048 blocks = 8 blocks/CU (full occupancy); needs 32 MB P.
// ---------------------------------------------------------------------------
template <int NC>
__global__ __launch_bounds__(256, 8) void k1_partial(
    const float* __restrict__ key_in, const float* __restrict__ value,
    float* __restrict__ P)
{
    const int KPC = SK / NC;
    const int chunk = blockIdx.x & (NC - 1);
    const int bh    = blockIdx.x / NC;
    const int b = bh >> 4, h = bh & 15;
    const int tid = threadIdx.x;
    const int d4 = tid & 15, ng = tid >> 4;
    const int d0 = d4 * 4, n0 = ng * 2;

    __shared__ float2 csK[KBATCH][NN];   // 16 KB: (cos, sin) per (key, n)

    float accC0[4] = {0,0,0,0}, accS0[4] = {0,0,0,0};
    float accC1[4] = {0,0,0,0}, accS1[4] = {0,0,0,0};

    for (int bb = 0; bb < KPC / KBATCH; ++bb) {
        const int kbase = chunk * KPC + bb * KBATCH;
        // --- stage sincos for this key batch (KBATCH*NN = 2048 pairs) ---
        #pragma unroll
        for (int i = 0; i < (KBATCH * NN) / 256; ++i) {  // 8 per thread
            int idx = tid + i * 256;
            int kl = idx >> 5, n = idx & 31;
            float kv = key_in[(size_t)(b * SK + kbase + kl) * HH + h];
            float s, c;
            __sincosf(freq_of(n) * kv, &s, &c);
            csK[kl][n] = make_float2(c, s);
        }
        __syncthreads();

        const float* vbase = value + (size_t)(b * SK + kbase) * (HH * DD) + h * DD + d0;
        #pragma unroll 4
        for (int kl = 0; kl < KBATCH; ++kl) {
            float4 v = *(const float4*)(vbase + (size_t)kl * (HH * DD));
            float2 cs0 = csK[kl][n0];
            float2 cs1 = csK[kl][n0 + 1];
            accC0[0] += cs0.x * v.x; accC0[1] += cs0.x * v.y;
            accC0[2] += cs0.x * v.z; accC0[3] += cs0.x * v.w;
            accS0[0] += cs0.y * v.x; accS0[1] += cs0.y * v.y;
            accS0[2] += cs0.y * v.z; accS0[3] += cs0.y * v.w;
            accC1[0] += cs1.x * v.x; accC1[1] += cs1.x * v.y;
            accC1[2] += cs1.x * v.z; accC1[3] += cs1.x * v.w;
            accS1[0] += cs1.y * v.x; accS1[1] += cs1.y * v.y;
            accS1[2] += cs1.y * v.z; accS1[3] += cs1.y * v.w;
        }
        __syncthreads();
    }

    // write partials
    float* Pb = P + ((size_t)chunk * 64 + bh) * (2 * NN * DD);
    *(float4*)(Pb + (size_t)n0 * DD + d0)              = make_float4(accC0[0], accC0[1], accC0[2], accC0[3]);
    *(float4*)(Pb + (size_t)(n0 + 1) * DD + d0)        = make_float4(accC1[0], accC1[1], accC1[2], accC1[3]);
    *(float4*)(Pb + 2048 + (size_t)n0 * DD + d0)       = make_float4(accS0[0], accS0[1], accS0[2], accS0[3]);
    *(float4*)(Pb + 2048 + (size_t)(n0 + 1) * DD + d0) = make_float4(accS1[0], accS1[1], accS1[2], accS1[3]);
}

// ---------------------------------------------------------------------------
// Kernel 1b: reduce the NC chunk partials.  CS[bh][cs][n][d] (262144 floats).
// ---------------------------------------------------------------------------
template <int NC>
__global__ __launch_bounds__(256) void k1_reduce(
    const float* __restrict__ P, float* __restrict__ CS)
{
    int gid = blockIdx.x * 256 + threadIdx.x;  // 0 .. 262143
    float acc = 0.f;
    #pragma unroll
    for (int c = 0; c < NC; ++c)
        acc += P[(size_t)c * (64 * 2 * NN * DD) + gid];
    CS[gid] = acc;
}

// ---------------------------------------------------------------------------
// Kernel 2: out[q,d] = sum_n A[q,n]*C[n,d] + B[q,n]*S[n,d]
// A = ra*cos(f_n q) + ia*sin(f_n q);  B = ra*sin(f_n q) - ia*cos(f_n q)
// Grid: 2048 blocks = 64 (b,h) x 32 q-chunks of 128 queries.
// Thread: d4 = tid&15 (4 d), qg = tid>>4 (8 q) -> 8x4 register tile.
// A/B stored n-paired as float4 with column swizzle col=(n2+qg)&15 so the
// 4 distinct addresses per wave hit distinct banks (conflict-free).
// ---------------------------------------------------------------------------
__global__ __launch_bounds__(256) void k2_out(
    const float* __restrict__ query, const float* __restrict__ ramps,
    const float* __restrict__ iamps, const float* __restrict__ CS,
    float* __restrict__ out)
{
    const int bh = blockIdx.x >> 5;
    const int qc = blockIdx.x & 31;
    const int b = bh >> 4, h = bh & 15;
    const int qbase = qc * 128;
    const int tid = threadIdx.x;

    __shared__ float  csC[NN][DD];        // 8 KB  (C plane)
    __shared__ float  csS[NN][DD];        // 8 KB  (S plane)
    __shared__ float4 abQ[128][16];       // 32 KB: (A_n,B_n,A_n1,B_n1) swizzled

    // load C/S planes (each 2048 floats), coalesced
    const float* CSb = CS + (size_t)bh * (2 * NN * DD);
    #pragma unroll
    for (int i = 0; i < 8; ++i) {
        int idx = tid + i * 256;
        ((float*)csC)[idx] = CSb[idx];
        ((float*)csS)[idx] = CSb[2048 + idx];
    }
    // stage A/B for 128 queries x 32 n  (16 sincos per thread)
    #pragma unroll
    for (int i = 0; i < 16; ++i) {
        int idx = tid + i * 256;
        int ql = idx >> 5, n = idx & 31;
        float qv = query[(size_t)(b * SQ + qbase + ql) * HH + h];
        float ra = ramps[h * NN + n], ia = iamps[h * NN + n];
        float s, c;
        __sincosf(freq_of(n) * qv, &s, &c);
        int col = ((n >> 1) + (ql >> 3)) & 15;
        ((float2*)&abQ[ql][col])[n & 1] = make_float2(ra * c + ia * s, ra * s - ia * c);
    }
    __syncthreads();

    const int d4 = tid & 15, qg = tid >> 4;   // qg: 0..15, owns 8 queries
    const int d0 = d4 * 4;
    float acc[8][4];
    #pragma unroll
    for (int qi = 0; qi < 8; ++qi)
        #pragma unroll
        for (int dj = 0; dj < 4; ++dj) acc[qi][dj] = 0.f;

    #pragma unroll 4
    for (int n2 = 0; n2 < 16; ++n2) {
        const int n = n2 * 2;
        float4 c0 = *(const float4*)&csC[n][d0];
        float4 s0 = *(const float4*)&csS[n][d0];
        float4 c1 = *(const float4*)&csC[n + 1][d0];
        float4 s1 = *(const float4*)&csS[n + 1][d0];
        const int col = (n2 + qg) & 15;
        #pragma unroll
        for (int qi = 0; qi < 8; ++qi) {
            float4 ab = abQ[qg * 8 + qi][col];  // (A_n, B_n, A_n1, B_n1)
            acc[qi][0] += ab.x * c0.x + ab.y * s0.x + ab.z * c1.x + ab.w * s1.x;
            acc[qi][1] += ab.x * c0.y + ab.y * s0.y + ab.z * c1.y + ab.w * s1.y;
            acc[qi][2] += ab.x * c0.z + ab.y * s0.z + ab.z * c1.z + ab.w * s1.z;
            acc[qi][3] += ab.x * c0.w + ab.y * s0.w + ab.z * c1.w + ab.w * s1.w;
        }
    }

    float* ob = out + (size_t)(b * SQ + qbase) * (HH * DD) + h * DD + d0;
    #pragma unroll
    for (int qi = 0; qi < 8; ++qi) {
        int q = qg * 8 + qi;
        *(float4*)(ob + (size_t)q * (HH * DD)) =
            make_float4(acc[qi][0], acc[qi][1], acc[qi][2], acc[qi][3]);
    }
}

extern "C" void kernel_launch(void* const* d_in, const int* in_sizes, int n_in,
                              void* d_out, int out_size, void* d_ws, size_t ws_size,
                              hipStream_t stream) {
    const float* key_in = (const float*)d_in[0];
    const float* value  = (const float*)d_in[1];
    const float* query  = (const float*)d_in[2];
    const float* ramps  = (const float*)d_in[3];
    const float* iamps  = (const float*)d_in[4];
    float* out = (float*)d_out;

    const size_t CS_FLOATS = 64 * 2 * NN * DD;               // 262144
    const size_t P32_FLOATS = (size_t)32 * CS_FLOATS;        // 8.4M floats = 32 MB
    const size_t need32 = (P32_FLOATS + CS_FLOATS) * sizeof(float);

    float* P = (float*)d_ws;

    if (ws_size >= need32) {
        // full-occupancy path: 2048 blocks = 8 blocks/CU
        float* CS = P + P32_FLOATS;
        hipLaunchKernelGGL((k1_partial<32>), dim3(64 * 32), dim3(256), 0, stream,
                           key_in, value, P);
        hipLaunchKernelGGL((k1_reduce<32>), dim3(CS_FLOATS / 256), dim3(256), 0, stream,
                           P, CS);
        hipLaunchKernelGGL(k2_out, dim3(64 * 32), dim3(256), 0, stream,
                           query, ramps, iamps, CS, out);
    } else {
        // fallback: proven 9 MB footprint
        float* CS = P + (size_t)8 * CS_FLOATS;
        hipLaunchKernelGGL((k1_partial<8>), dim3(64 * 8), dim3(256), 0, stream,
                           key_in, value, P);
        hipLaunchKernelGGL((k1_reduce<8>), dim3(CS_FLOATS / 256), dim3(256), 0, stream,
                           P, CS);
        hipLaunchKernelGGL(k2_out, dim3(64 * 32), dim3(256), 0, stream,
                           query, ramps, iamps, CS, out);
    }
}